// Round 4
// baseline (639.797 us; speedup 1.0000x reference)
//
#include <hip/hip_runtime.h>

#define NN 4096
#define DD 512
#define FF 512
#define HH 4

typedef _Float16 f16;
typedef f16 f16x8 __attribute__((ext_vector_type(8)));
typedef f16 f16x4 __attribute__((ext_vector_type(4)));
typedef float f32x4 __attribute__((ext_vector_type(4)));
typedef unsigned short u16;

#define BM 128
#define BN 64
#define BK 32
#define LDK 40  // padded LDS row stride (f16 elems): 80 B rows, 16B-aligned, breaks bank aliasing

template <class A, class B> struct same_t { static constexpr int v = 0; };
template <class A> struct same_t<A, A> { static constexpr int v = 1; };

__device__ __forceinline__ float bits2f(unsigned int u) {
    float f; __builtin_memcpy(&f, &u, 4); return f;
}
__device__ __forceinline__ unsigned int f2bits(float f) {
    unsigned int u; __builtin_memcpy(&u, &f, 4); return u;
}
// load input element as float, whatever the storage dtype
template <typename T>
__device__ __forceinline__ float ldv(const T* p, size_t i) {
    if constexpr (same_t<T, float>::v) return p[i];
    else return bits2f(((unsigned int)p[i]) << 16);   // bf16 -> f32 (exact)
}
__device__ __forceinline__ u16 f2b(float f) {         // f32 -> bf16 RNE
    unsigned int u = f2bits(f);
    unsigned int r = u + 0x7FFFu + ((u >> 16) & 1u);
    return (u16)(r >> 16);
}

// ---------------- static device workspace (~31 MB, fully rewritten every call) ----------------
__device__ int g_isf32;
__device__ __attribute__((aligned(16))) f16 g_nodesH[NN * DD];       //  4 MB
__device__ __attribute__((aligned(16))) f16 g_XH[NN * DD];           //  4 MB  edges+labels
__device__ __attribute__((aligned(16))) f16 g_WeTH[FF * DD];         //  0.5 MB  We^T[f][d]
__device__ __attribute__((aligned(16))) f16 g_WTH[HH * FF * DD];     //  2 MB  W^T[h][f][d]
__device__ __attribute__((aligned(16))) f16 g_eH[FF * NN];           //  4 MB  e^T[f][n]
__device__ __attribute__((aligned(16))) f16 g_featsH[HH * FF * NN];  // 16 MB  (feats+e)^T
__device__ float g_beF[FF];
__device__ float g_bF[HH * FF];
__device__ float g_tu[HH * DD], g_tv[HH * DD], g_bu[HH], g_bv[HH];
__device__ float g_p[HH * NN], g_q[HH * NN], g_M[HH * NN], g_sc[HH * NN];

// ---------------- dtype probe: fp32 dwords have ~uniform bits[14:7]; bf16-pair dwords
//                  have a bf16 exponent there (concentrated near 127) ----------------
__global__ void k_probe(const unsigned int* __restrict__ raw) {
    __shared__ int cnt;
    if (threadIdx.x == 0) cnt = 0;
    __syncthreads();
    unsigned int w = raw[threadIdx.x];          // first 256 dwords of nodes
    unsigned int e_low = (w >> 7) & 0xFFu;
    if (e_low >= 115u && e_low <= 133u) atomicAdd(&cnt, 1);
    __syncthreads();
    if (threadIdx.x == 0) g_isf32 = (cnt < 128) ? 1 : 0;
}

// ---------------- ingress: convert all inputs to canonical fp16/fp32 staging ----------------
template <typename T>
__global__ void k_convert(const T* __restrict__ nodes, const T* __restrict__ edges,
                          const T* __restrict__ labels, const T* __restrict__ We,
                          const T* __restrict__ W, const T* __restrict__ be,
                          const T* __restrict__ b) {
    if (g_isf32 != same_t<T, float>::v) return;
    int id = blockIdx.x * 256 + threadIdx.x;    // 21514 blocks -> 5,507,584 ids
    const int NDE = NN * DD;
    if (id < NDE) { g_nodesH[id] = (f16)ldv(nodes, (size_t)id); return; }
    id -= NDE;
    if (id < NDE) { g_XH[id] = (f16)(ldv(edges, (size_t)id) + ldv(labels, (size_t)id)); return; }
    id -= NDE;
    if (id < FF * DD) {
        int f = id >> 9, d = id & 511;
        g_WeTH[id] = (f16)ldv(We, (size_t)d * FF + f);
        return;
    }
    id -= FF * DD;
    if (id < HH * FF * DD) {
        int h = id >> 18, fd = id & 262143, f = fd >> 9, d = fd & 511;
        g_WTH[id] = (f16)ldv(W, (size_t)h * DD * FF + (size_t)d * FF + f);
        return;
    }
    id -= HH * FF * DD;
    if (id < FF) { g_beF[id] = ldv(be, (size_t)id); return; }
    id -= FF;
    if (id < HH * FF) { g_bF[id] = ldv(b, (size_t)id); return; }
}

// ---------------- exact fp32 score path, part 1: t_u[h][d]=sum_f W u, bu[h]=b.u ----------------
template <typename T>
__global__ __launch_bounds__(256) void k_uvproj(const T* __restrict__ W, const T* __restrict__ b,
                                                const T* __restrict__ u, const T* __restrict__ v) {
    if (g_isf32 != same_t<T, float>::v) return;
    int row = blockIdx.x * 4 + (threadIdx.x >> 6);    // 513 blocks -> 2052 rows
    int lane = threadIdx.x & 63;
    float su = 0.f, sv = 0.f;
    if (row < HH * DD) {
        int h = row >> 9, d = row & 511;
        size_t wb = (size_t)h * DD * FF + (size_t)d * FF;
#pragma unroll
        for (int j = 0; j < 8; ++j) {
            int f = lane + 64 * j;
            float wv = ldv(W, wb + f);
            su += wv * ldv(u, (size_t)h * FF + f);
            sv += wv * ldv(v, (size_t)h * FF + f);
        }
    } else if (row < HH * DD + HH) {
        int h = row - HH * DD;
#pragma unroll
        for (int j = 0; j < 8; ++j) {
            int f = lane + 64 * j;
            float bvv = ldv(b, (size_t)h * FF + f);
            su += bvv * ldv(u, (size_t)h * FF + f);
            sv += bvv * ldv(v, (size_t)h * FF + f);
        }
    }
#pragma unroll
    for (int m = 1; m < 64; m <<= 1) {
        su += __shfl_xor(su, m, 64);
        sv += __shfl_xor(sv, m, 64);
    }
    if (lane == 0 && row < HH * DD + HH) {
        if (row < HH * DD) { g_tu[row] = su; g_tv[row] = sv; }
        else { g_bu[row - HH * DD] = su; g_bv[row - HH * DD] = sv; }
    }
}

// ---------------- part 2: p[h][n] = nodes[n].t_u[h] + bu[h];  q likewise ----------------
__global__ __launch_bounds__(256) void k_pq() {
    int row = blockIdx.x * 4 + (threadIdx.x >> 6);    // 4096 blocks -> 16384 rows = H*N
    int lane = threadIdx.x & 63;
    int h = row >> 12, n = row & 4095;
    const f16* nb = g_nodesH + (size_t)n * DD;
    const float* tu = g_tu + h * DD;
    const float* tv = g_tv + h * DD;
    float pa = 0.f, qa = 0.f;
#pragma unroll
    for (int j = 0; j < 8; ++j) {
        int d = lane + 64 * j;
        float nv = (float)nb[d];
        pa += nv * tu[d];
        qa += nv * tv[d];
    }
#pragma unroll
    for (int m = 1; m < 64; m <<= 1) {
        pa += __shfl_xor(pa, m, 64);
        qa += __shfl_xor(qa, m, 64);
    }
    if (lane == 0) {
        g_p[row] = pa + g_bu[h];
        g_q[row] = qa + g_bv[h];
    }
}

// ---------------- GEMM1: eH[f][n] = f16((X @ We)[n][f] + be[f]) ----------------
__global__ __launch_bounds__(256) void k_gemm_e() {
    __shared__ f16 As[BM * LDK];
    __shared__ f16 Bs[BN * LDK];
    int tid = threadIdx.x;
    int n0 = blockIdx.x * BM, f0 = blockIdx.y * BN;
    int lane = tid & 63, wave = tid >> 6, wr = wave >> 1, wc = wave & 1;
    int c = lane & 15, g = lane >> 4;
    int arow = tid >> 2, kpart = (tid & 3) * 8;
    f32x4 acc[4][2] = {};
    for (int kk = 0; kk < DD; kk += BK) {
        f16x8 a0 = *(const f16x8*)(g_XH + (size_t)(n0 + arow) * DD + kk + kpart);
        f16x8 a1 = *(const f16x8*)(g_XH + (size_t)(n0 + arow + 64) * DD + kk + kpart);
        f16x8 b0 = *(const f16x8*)(g_WeTH + (size_t)(f0 + arow) * DD + kk + kpart);
        __syncthreads();
        *(f16x8*)&As[arow * LDK + kpart] = a0;
        *(f16x8*)&As[(arow + 64) * LDK + kpart] = a1;
        *(f16x8*)&Bs[arow * LDK + kpart] = b0;
        __syncthreads();
        f16x8 af[4], bfr[2];
#pragma unroll
        for (int i = 0; i < 4; ++i) af[i] = *(const f16x8*)&As[(wr * 64 + i * 16 + c) * LDK + g * 8];
#pragma unroll
        for (int jj = 0; jj < 2; ++jj) bfr[jj] = *(const f16x8*)&Bs[(wc * 32 + jj * 16 + c) * LDK + g * 8];
#pragma unroll
        for (int i = 0; i < 4; ++i)
#pragma unroll
            for (int jj = 0; jj < 2; ++jj)
                acc[i][jj] = __builtin_amdgcn_mfma_f32_16x16x32_f16(af[i], bfr[jj], acc[i][jj], 0, 0, 0);
    }
#pragma unroll
    for (int jj = 0; jj < 2; ++jj) {
        int f = f0 + wc * 32 + jj * 16 + c;
        float bv = g_beF[f];
#pragma unroll
        for (int i = 0; i < 4; ++i) {
            int r0 = n0 + wr * 64 + i * 16 + g * 4;
            f16x4 ov;
#pragma unroll
            for (int rr = 0; rr < 4; ++rr) ov[rr] = (f16)(acc[i][jj][rr] + bv);
            *(f16x4*)(g_eH + (size_t)f * NN + r0) = ov;
        }
    }
}

// ---------------- GEMM2: featsH[h][f][n] = f16((nodes @ W_h)[n][f] + b_h[f] + e[n][f]) ----------------
__global__ __launch_bounds__(256) void k_gemm_feats() {
    __shared__ f16 As[BM * LDK];
    __shared__ f16 Bs[BN * LDK];
    int tid = threadIdx.x;
    int h = blockIdx.z;
    int n0 = blockIdx.x * BM, f0 = blockIdx.y * BN;
    int lane = tid & 63, wave = tid >> 6, wr = wave >> 1, wc = wave & 1;
    int c = lane & 15, g = lane >> 4;
    int arow = tid >> 2, kpart = (tid & 3) * 8;
    const f16* BT = g_WTH + (size_t)h * DD * FF;
    f32x4 acc[4][2] = {};
    for (int kk = 0; kk < DD; kk += BK) {
        f16x8 a0 = *(const f16x8*)(g_nodesH + (size_t)(n0 + arow) * DD + kk + kpart);
        f16x8 a1 = *(const f16x8*)(g_nodesH + (size_t)(n0 + arow + 64) * DD + kk + kpart);
        f16x8 b0 = *(const f16x8*)(BT + (size_t)(f0 + arow) * DD + kk + kpart);
        __syncthreads();
        *(f16x8*)&As[arow * LDK + kpart] = a0;
        *(f16x8*)&As[(arow + 64) * LDK + kpart] = a1;
        *(f16x8*)&Bs[arow * LDK + kpart] = b0;
        __syncthreads();
        f16x8 af[4], bfr[2];
#pragma unroll
        for (int i = 0; i < 4; ++i) af[i] = *(const f16x8*)&As[(wr * 64 + i * 16 + c) * LDK + g * 8];
#pragma unroll
        for (int jj = 0; jj < 2; ++jj) bfr[jj] = *(const f16x8*)&Bs[(wc * 32 + jj * 16 + c) * LDK + g * 8];
#pragma unroll
        for (int i = 0; i < 4; ++i)
#pragma unroll
            for (int jj = 0; jj < 2; ++jj)
                acc[i][jj] = __builtin_amdgcn_mfma_f32_16x16x32_f16(af[i], bfr[jj], acc[i][jj], 0, 0, 0);
    }
#pragma unroll
    for (int jj = 0; jj < 2; ++jj) {
        int f = f0 + wc * 32 + jj * 16 + c;
        float bv = g_bF[h * FF + f];
#pragma unroll
        for (int i = 0; i < 4; ++i) {
            int r0 = n0 + wr * 64 + i * 16 + g * 4;
            f16x4 e4 = *(const f16x4*)(g_eH + (size_t)f * NN + r0);
            f16x4 ov;
#pragma unroll
            for (int rr = 0; rr < 4; ++rr)
                ov[rr] = (f16)(acc[i][jj][rr] + bv + (float)e4[rr]);
            *(f16x4*)(g_featsH + ((size_t)h * FF + f) * NN + r0) = ov;
        }
    }
}

// ---------------- per-row softmax stats: M = max_m lrelu(p*q_m); sc = 0.25/Z ----------------
__global__ __launch_bounds__(256) void k_msz() {
    __shared__ float qsh[NN];
    __shared__ float mred[256], zred[256];
    int h = blockIdx.y;
    int tid = threadIdx.x;
    for (int i = tid; i < NN; i += 256) qsh[i] = g_q[h * NN + i];
    __syncthreads();
    int nl = tid & 63, chunk = tid >> 6;             // 64 rows/block, 4 k-chunks of 1024
    int n = blockIdx.x * 64 + nl;
    float pv = g_p[h * NN + n];
    float m = -1e30f;
    int base = chunk * 1024;
    for (int i = 0; i < 1024; ++i) {
        float s = pv * qsh[base + i];
        s = fmaxf(s, 0.3f * s);                      // LeakyReLU(0.3)
        m = fmaxf(m, s);
    }
    float z = 0.f;
    for (int i = 0; i < 1024; ++i) {
        float s = pv * qsh[base + i];
        s = fmaxf(s, 0.3f * s);
        z += __expf(s - m);
    }
    mred[tid] = m; zred[tid] = z;
    __syncthreads();
    if (chunk == 0) {
        float m0 = mred[nl], m1 = mred[64 + nl], m2 = mred[128 + nl], m3 = mred[192 + nl];
        float M = fmaxf(fmaxf(m0, m1), fmaxf(m2, m3));
        float Z = zred[nl] * __expf(m0 - M) + zred[64 + nl] * __expf(m1 - M) +
                  zred[128 + nl] * __expf(m2 - M) + zred[192 + nl] * __expf(m3 - M);
        g_M[h * NN + n] = M;
        g_sc[h * NN + n] = 0.25f / Z;
    }
}

// ---------------- GEMM3 (heads fused): out[n][f] = relu(sum_h sum_m w_h[n][m]*featsH[h][f][m])
//                  attention weights regenerated on the fly during A-tile staging ----------------
template <typename T>
__global__ __launch_bounds__(256) void k_gemm_out(T* __restrict__ out) {
    if (g_isf32 != same_t<T, float>::v) return;
    __shared__ f16 As[BM * LDK];
    __shared__ f16 Bs[BN * LDK];
    int tid = threadIdx.x;
    int n0 = blockIdx.x * BM, f0 = blockIdx.y * BN;
    int lane = tid & 63, wave = tid >> 6, wr = wave >> 1, wc = wave & 1;
    int c = lane & 15, g = lane >> 4;
    int wn = tid >> 1;        // 0..127: A row this thread generates
    int half = tid & 1;       // which 16 of the 32 k's
    int brow = tid >> 2, kpart = (tid & 3) * 8;
    f32x4 acc[4][2] = {};
    for (int h = 0; h < HH; ++h) {
        float pv = g_p[h * NN + n0 + wn];
        float mv = g_M[h * NN + n0 + wn];
        float sv = g_sc[h * NN + n0 + wn];
        const f16* Bsrc = g_featsH + ((size_t)h * FF + f0) * NN;
        const float* qh = g_q + h * NN;
        for (int kk = 0; kk < NN; kk += BK) {
            f16x8 b0 = *(const f16x8*)(Bsrc + (size_t)brow * NN + kk + kpart);
            f32x4 q0 = *(const f32x4*)(qh + kk + half * 16);
            f32x4 q1 = *(const f32x4*)(qh + kk + half * 16 + 4);
            f32x4 q2 = *(const f32x4*)(qh + kk + half * 16 + 8);
            f32x4 q3 = *(const f32x4*)(qh + kk + half * 16 + 12);
            f16x8 w0, w1;
#pragma unroll
            for (int j = 0; j < 4; ++j) {
                float s = pv * q0[j];
                s = fmaxf(s, 0.3f * s);
                w0[j] = (f16)(__expf(s - mv) * sv);
            }
#pragma unroll
            for (int j = 0; j < 4; ++j) {
                float s = pv * q1[j];
                s = fmaxf(s, 0.3f * s);
                w0[4 + j] = (f16)(__expf(s - mv) * sv);
            }
#pragma unroll
            for (int j = 0; j < 4; ++j) {
                float s = pv * q2[j];
                s = fmaxf(s, 0.3f * s);
                w1[j] = (f16)(__expf(s - mv) * sv);
            }
#pragma unroll
            for (int j = 0; j < 4; ++j) {
                float s = pv * q3[j];
                s = fmaxf(s, 0.3f * s);
                w1[4 + j] = (f16)(__expf(s - mv) * sv);
            }
            __syncthreads();
            *(f16x8*)&As[wn * LDK + half * 16]     = w0;
            *(f16x8*)&As[wn * LDK + half * 16 + 8] = w1;
            *(f16x8*)&Bs[brow * LDK + kpart] = b0;
            __syncthreads();
            f16x8 af[4], bfr[2];
#pragma unroll
            for (int i = 0; i < 4; ++i) af[i] = *(const f16x8*)&As[(wr * 64 + i * 16 + c) * LDK + g * 8];
#pragma unroll
            for (int jj = 0; jj < 2; ++jj) bfr[jj] = *(const f16x8*)&Bs[(wc * 32 + jj * 16 + c) * LDK + g * 8];
#pragma unroll
            for (int i = 0; i < 4; ++i)
#pragma unroll
                for (int jj = 0; jj < 2; ++jj)
                    acc[i][jj] = __builtin_amdgcn_mfma_f32_16x16x32_f16(af[i], bfr[jj], acc[i][jj], 0, 0, 0);
        }
    }
#pragma unroll
    for (int jj = 0; jj < 2; ++jj) {
        int f = f0 + wc * 32 + jj * 16 + c;
#pragma unroll
        for (int i = 0; i < 4; ++i) {
            int r0 = n0 + wr * 64 + i * 16 + g * 4;
#pragma unroll
            for (int rr = 0; rr < 4; ++rr) {
                float val = fmaxf(acc[i][jj][rr], 0.f);
                if constexpr (same_t<T, float>::v)
                    out[(size_t)(r0 + rr) * FF + f] = val;
                else
                    out[(size_t)(r0 + rr) * FF + f] = f2b(val);
            }
        }
    }
}

extern "C" void kernel_launch(void* const* d_in, const int* in_sizes, int n_in,
                              void* d_out, int out_size, void* d_ws, size_t ws_size,
                              hipStream_t stream) {
    (void)in_sizes; (void)n_in; (void)out_size; (void)d_ws; (void)ws_size;

    k_probe<<<1, 256, 0, stream>>>((const unsigned int*)d_in[0]);

    // fp32 pipeline heads
    k_convert<float><<<21514, 256, 0, stream>>>(
        (const float*)d_in[0], (const float*)d_in[1], (const float*)d_in[2],
        (const float*)d_in[3], (const float*)d_in[5], (const float*)d_in[4],
        (const float*)d_in[6]);
    // bf16 pipeline heads
    k_convert<u16><<<21514, 256, 0, stream>>>(
        (const u16*)d_in[0], (const u16*)d_in[1], (const u16*)d_in[2],
        (const u16*)d_in[3], (const u16*)d_in[5], (const u16*)d_in[4],
        (const u16*)d_in[6]);

    k_uvproj<float><<<513, 256, 0, stream>>>(
        (const float*)d_in[5], (const float*)d_in[6], (const float*)d_in[7], (const float*)d_in[8]);
    k_uvproj<u16><<<513, 256, 0, stream>>>(
        (const u16*)d_in[5], (const u16*)d_in[6], (const u16*)d_in[7], (const u16*)d_in[8]);

    k_pq<<<4096, 256, 0, stream>>>();
    k_gemm_e<<<dim3(32, 8), 256, 0, stream>>>();
    k_gemm_feats<<<dim3(32, 8, 4), 256, 0, stream>>>();
    k_msz<<<dim3(64, 4), 256, 0, stream>>>();

    k_gemm_out<float><<<dim3(32, 8), 256, 0, stream>>>((float*)d_out);
    k_gemm_out<u16><<<dim3(32, 8), 256, 0, stream>>>((u16*)d_out);
}

// Round 5
// 349.429 us; speedup vs baseline: 1.8310x; 1.8310x over previous
//
#include <hip/hip_runtime.h>

#define NN 4096
#define DD 512
#define FF 512
#define HH 4

typedef _Float16 f16;
typedef f16 f16x8 __attribute__((ext_vector_type(8)));
typedef f16 f16x4 __attribute__((ext_vector_type(4)));
typedef float f32x4 __attribute__((ext_vector_type(4)));

#define BM 128
#define BN 64
#define BK 32
#define LDK 40   // padded LDS row stride (f16 elems): 80 B rows, 16B-aligned

// tile for k_gemm_out: 128x128, 2x2 waves of 64x64
#define ON 128

// ---------------- static device workspace (fully rewritten every call) ----------------
__device__ __attribute__((aligned(16))) f16 g_nodesH[NN * DD];       //  4 MB
__device__ __attribute__((aligned(16))) f16 g_XH[NN * DD];           //  4 MB  edges+labels
__device__ __attribute__((aligned(16))) f16 g_WeTH[FF * DD];         //  0.5 MB  We^T[f][d]
__device__ __attribute__((aligned(16))) f16 g_WTH[HH * FF * DD];     //  2 MB  W^T[h][f][d]
__device__ __attribute__((aligned(16))) f16 g_eH[FF * NN];           //  4 MB  e^T[f][n]
__device__ __attribute__((aligned(16))) f16 g_featsH[HH * FF * NN];  // 16 MB  (feats+e)^T
__device__ __attribute__((aligned(16))) float g_oacc[HH * NN * FF];  // 32 MB  per-head partials
__device__ float g_beF[FF];
__device__ float g_bF[HH * FF];
__device__ float g_tu[HH * DD], g_tv[HH * DD], g_bu[HH], g_bv[HH];
__device__ float g_p[HH * NN], g_q[HH * NN], g_M[HH * NN], g_sc[HH * NN];

// ---------------- ingress: fp32 -> f16 staging (+ weight transposes, X=edges+labels) ----------------
__global__ void k_convert(const float* __restrict__ nodes, const float* __restrict__ edges,
                          const float* __restrict__ labels, const float* __restrict__ We,
                          const float* __restrict__ W, const float* __restrict__ be,
                          const float* __restrict__ b) {
    int id = blockIdx.x * 256 + threadIdx.x;    // 21514 blocks -> 5,507,584 ids
    const int NDE = NN * DD;
    if (id < NDE) { g_nodesH[id] = (f16)nodes[id]; return; }
    id -= NDE;
    if (id < NDE) { g_XH[id] = (f16)(edges[id] + labels[id]); return; }
    id -= NDE;
    if (id < FF * DD) {
        int f = id >> 9, d = id & 511;
        g_WeTH[id] = (f16)We[(size_t)d * FF + f];
        return;
    }
    id -= FF * DD;
    if (id < HH * FF * DD) {
        int h = id >> 18, fd = id & 262143, f = fd >> 9, d = fd & 511;
        g_WTH[id] = (f16)W[(size_t)h * DD * FF + (size_t)d * FF + f];
        return;
    }
    id -= HH * FF * DD;
    if (id < FF) { g_beF[id] = be[id]; return; }
    id -= FF;
    if (id < HH * FF) { g_bF[id] = b[id]; return; }
}

// ---------------- exact fp32 score path, part 1: t_u[h][d]=sum_f W[h][d][f]*u[h][f]; bu[h]=b.u ----------------
__global__ __launch_bounds__(256) void k_uvproj(const float* __restrict__ W, const float* __restrict__ b,
                                                const float* __restrict__ u, const float* __restrict__ v) {
    int row = blockIdx.x * 4 + (threadIdx.x >> 6);    // 513 blocks -> 2052 rows
    int lane = threadIdx.x & 63;
    float su = 0.f, sv = 0.f;
    if (row < HH * DD) {
        int h = row >> 9, d = row & 511;
        size_t wb = (size_t)h * DD * FF + (size_t)d * FF;
#pragma unroll
        for (int j = 0; j < 8; ++j) {
            int f = lane + 64 * j;
            float wv = W[wb + f];
            su += wv * u[(size_t)h * FF + f];
            sv += wv * v[(size_t)h * FF + f];
        }
    } else if (row < HH * DD + HH) {
        int h = row - HH * DD;
#pragma unroll
        for (int j = 0; j < 8; ++j) {
            int f = lane + 64 * j;
            float bvv = b[(size_t)h * FF + f];
            su += bvv * u[(size_t)h * FF + f];
            sv += bvv * v[(size_t)h * FF + f];
        }
    }
#pragma unroll
    for (int m = 1; m < 64; m <<= 1) {
        su += __shfl_xor(su, m, 64);
        sv += __shfl_xor(sv, m, 64);
    }
    if (lane == 0 && row < HH * DD + HH) {
        if (row < HH * DD) { g_tu[row] = su; g_tv[row] = sv; }
        else { g_bu[row - HH * DD] = su; g_bv[row - HH * DD] = sv; }
    }
}

// ---------------- part 2: p[h][n] = nodes[n].t_u[h] + bu[h];  q likewise ----------------
__global__ __launch_bounds__(256) void k_pq() {
    int row = blockIdx.x * 4 + (threadIdx.x >> 6);    // 4096 blocks -> 16384 rows = H*N
    int lane = threadIdx.x & 63;
    int h = row >> 12, n = row & 4095;
    const f16* nb = g_nodesH + (size_t)n * DD;
    const float* tu = g_tu + h * DD;
    const float* tv = g_tv + h * DD;
    float pa = 0.f, qa = 0.f;
#pragma unroll
    for (int j = 0; j < 8; ++j) {
        int d = lane + 64 * j;
        float nv = (float)nb[d];
        pa += nv * tu[d];
        qa += nv * tv[d];
    }
#pragma unroll
    for (int m = 1; m < 64; m <<= 1) {
        pa += __shfl_xor(pa, m, 64);
        qa += __shfl_xor(qa, m, 64);
    }
    if (lane == 0) {
        g_p[row] = pa + g_bu[h];
        g_q[row] = qa + g_bv[h];
    }
}

// ---------------- GEMM1: eH[f][n] = f16((X @ We)[n][f] + be[f]) ----------------
__global__ __launch_bounds__(256) void k_gemm_e() {
    __shared__ f16 As[BM * LDK];
    __shared__ f16 Bs[BN * LDK];
    int tid = threadIdx.x;
    int n0 = blockIdx.x * BM, f0 = blockIdx.y * BN;
    int lane = tid & 63, wave = tid >> 6, wr = wave >> 1, wc = wave & 1;
    int c = lane & 15, g = lane >> 4;
    int arow = tid >> 2, kpart = (tid & 3) * 8;
    f32x4 acc[4][2] = {};
    for (int kk = 0; kk < DD; kk += BK) {
        f16x8 a0 = *(const f16x8*)(g_XH + (size_t)(n0 + arow) * DD + kk + kpart);
        f16x8 a1 = *(const f16x8*)(g_XH + (size_t)(n0 + arow + 64) * DD + kk + kpart);
        f16x8 b0 = *(const f16x8*)(g_WeTH + (size_t)(f0 + arow) * DD + kk + kpart);
        __syncthreads();
        *(f16x8*)&As[arow * LDK + kpart] = a0;
        *(f16x8*)&As[(arow + 64) * LDK + kpart] = a1;
        *(f16x8*)&Bs[arow * LDK + kpart] = b0;
        __syncthreads();
        f16x8 af[4], bfr[2];
#pragma unroll
        for (int i = 0; i < 4; ++i) af[i] = *(const f16x8*)&As[(wr * 64 + i * 16 + c) * LDK + g * 8];
#pragma unroll
        for (int jj = 0; jj < 2; ++jj) bfr[jj] = *(const f16x8*)&Bs[(wc * 32 + jj * 16 + c) * LDK + g * 8];
#pragma unroll
        for (int i = 0; i < 4; ++i)
#pragma unroll
            for (int jj = 0; jj < 2; ++jj)
                acc[i][jj] = __builtin_amdgcn_mfma_f32_16x16x32_f16(af[i], bfr[jj], acc[i][jj], 0, 0, 0);
    }
#pragma unroll
    for (int jj = 0; jj < 2; ++jj) {
        int f = f0 + wc * 32 + jj * 16 + c;
        float bv = g_beF[f];
#pragma unroll
        for (int i = 0; i < 4; ++i) {
            int r0 = n0 + wr * 64 + i * 16 + g * 4;
            f16x4 ov;
#pragma unroll
            for (int rr = 0; rr < 4; ++rr) ov[rr] = (f16)(acc[i][jj][rr] + bv);
            *(f16x4*)(g_eH + (size_t)f * NN + r0) = ov;
        }
    }
}

// ---------------- GEMM2: featsH[h][f][n] = f16((nodes @ W_h)[n][f] + b_h[f] + e[n][f]) ----------------
__global__ __launch_bounds__(256) void k_gemm_feats() {
    __shared__ f16 As[BM * LDK];
    __shared__ f16 Bs[BN * LDK];
    int tid = threadIdx.x;
    int h = blockIdx.z;
    int n0 = blockIdx.x * BM, f0 = blockIdx.y * BN;
    int lane = tid & 63, wave = tid >> 6, wr = wave >> 1, wc = wave & 1;
    int c = lane & 15, g = lane >> 4;
    int arow = tid >> 2, kpart = (tid & 3) * 8;
    const f16* BT = g_WTH + (size_t)h * DD * FF;
    f32x4 acc[4][2] = {};
    for (int kk = 0; kk < DD; kk += BK) {
        f16x8 a0 = *(const f16x8*)(g_nodesH + (size_t)(n0 + arow) * DD + kk + kpart);
        f16x8 a1 = *(const f16x8*)(g_nodesH + (size_t)(n0 + arow + 64) * DD + kk + kpart);
        f16x8 b0 = *(const f16x8*)(BT + (size_t)(f0 + arow) * DD + kk + kpart);
        __syncthreads();
        *(f16x8*)&As[arow * LDK + kpart] = a0;
        *(f16x8*)&As[(arow + 64) * LDK + kpart] = a1;
        *(f16x8*)&Bs[arow * LDK + kpart] = b0;
        __syncthreads();
        f16x8 af[4], bfr[2];
#pragma unroll
        for (int i = 0; i < 4; ++i) af[i] = *(const f16x8*)&As[(wr * 64 + i * 16 + c) * LDK + g * 8];
#pragma unroll
        for (int jj = 0; jj < 2; ++jj) bfr[jj] = *(const f16x8*)&Bs[(wc * 32 + jj * 16 + c) * LDK + g * 8];
#pragma unroll
        for (int i = 0; i < 4; ++i)
#pragma unroll
            for (int jj = 0; jj < 2; ++jj)
                acc[i][jj] = __builtin_amdgcn_mfma_f32_16x16x32_f16(af[i], bfr[jj], acc[i][jj], 0, 0, 0);
    }
#pragma unroll
    for (int jj = 0; jj < 2; ++jj) {
        int f = f0 + wc * 32 + jj * 16 + c;
        float bv = g_bF[h * FF + f];
#pragma unroll
        for (int i = 0; i < 4; ++i) {
            int r0 = n0 + wr * 64 + i * 16 + g * 4;
            f16x4 e4 = *(const f16x4*)(g_eH + (size_t)f * NN + r0);
            f16x4 ov;
#pragma unroll
            for (int rr = 0; rr < 4; ++rr)
                ov[rr] = (f16)(acc[i][jj][rr] + bv + (float)e4[rr]);
            *(f16x4*)(g_featsH + ((size_t)h * FF + f) * NN + r0) = ov;
        }
    }
}

// ---------------- per-row softmax stats: M = max_m lrelu(p*q_m); sc = 0.25/Z ----------------
// grid (256, 4): 16 rows/block, 16 k-chunks of 256
__global__ __launch_bounds__(256) void k_msz() {
    __shared__ float qsh[NN];          // 16 KB
    __shared__ float mred[256], zred[256];
    int h = blockIdx.y;
    int tid = threadIdx.x;
    for (int i = tid; i < NN; i += 256) qsh[i] = g_q[h * NN + i];
    __syncthreads();
    int nl = tid & 15, chunk = tid >> 4;
    int n = blockIdx.x * 16 + nl;
    float pv = g_p[h * NN + n];
    float m = -1e30f;
    int base = chunk * 256;
    for (int i = 0; i < 256; ++i) {
        float s = pv * qsh[base + i];
        s = fmaxf(s, 0.3f * s);                      // LeakyReLU(0.3)
        m = fmaxf(m, s);
    }
    float z = 0.f;
    for (int i = 0; i < 256; ++i) {
        float s = pv * qsh[base + i];
        s = fmaxf(s, 0.3f * s);
        z += __expf(s - m);
    }
    mred[tid] = m; zred[tid] = z;
    __syncthreads();
    if (chunk == 0) {
        float M = -1e30f;
#pragma unroll
        for (int t = 0; t < 16; ++t) M = fmaxf(M, mred[t * 16 + nl]);
        float Z = 0.f;
#pragma unroll
        for (int t = 0; t < 16; ++t) Z += zred[t * 16 + nl] * __expf(mred[t * 16 + nl] - M);
        g_M[h * NN + n] = M;
        g_sc[h * NN + n] = 0.25f / Z;
    }
}

// ---------------- GEMM3 (per head): oacc[h][n][f] = sum_m w_h[n][m]*featsH[h][f][m]
//                  128x128 tile, 2x2 waves of 64x64; weights regenerated on the fly ----------------
__global__ __launch_bounds__(256) void k_gemm_out() {
    __shared__ f16 As[BM * LDK];       // 128 x 32 weights
    __shared__ f16 Bs[ON * LDK];       // 128 x 32 feats
    int tid = threadIdx.x;
    int h = blockIdx.z;
    int n0 = blockIdx.x * BM, f0 = blockIdx.y * ON;
    int lane = tid & 63, wave = tid >> 6, wr = wave >> 1, wc = wave & 1;
    int c = lane & 15, g = lane >> 4;
    int wn = tid >> 1;        // 0..127: row this thread stages (A weights AND B feats)
    int half = tid & 1;       // which 16 of the 32 k's
    float pv = g_p[h * NN + n0 + wn];
    float mv = g_M[h * NN + n0 + wn];
    float sv = g_sc[h * NN + n0 + wn];
    const f16* Bsrc = g_featsH + ((size_t)h * FF + f0) * NN;
    const float* qh = g_q + h * NN;
    f32x4 acc[4][4] = {};
    for (int kk = 0; kk < NN; kk += BK) {
        f16x8 b0 = *(const f16x8*)(Bsrc + (size_t)wn * NN + kk + half * 16);
        f16x8 b1 = *(const f16x8*)(Bsrc + (size_t)wn * NN + kk + half * 16 + 8);
        f32x4 q0 = *(const f32x4*)(qh + kk + half * 16);
        f32x4 q1 = *(const f32x4*)(qh + kk + half * 16 + 4);
        f32x4 q2 = *(const f32x4*)(qh + kk + half * 16 + 8);
        f32x4 q3 = *(const f32x4*)(qh + kk + half * 16 + 12);
        f16x8 w0, w1;
#pragma unroll
        for (int j = 0; j < 4; ++j) {
            float s = pv * q0[j];
            s = fmaxf(s, 0.3f * s);
            w0[j] = (f16)(__expf(s - mv) * sv);
        }
#pragma unroll
        for (int j = 0; j < 4; ++j) {
            float s = pv * q1[j];
            s = fmaxf(s, 0.3f * s);
            w0[4 + j] = (f16)(__expf(s - mv) * sv);
        }
#pragma unroll
        for (int j = 0; j < 4; ++j) {
            float s = pv * q2[j];
            s = fmaxf(s, 0.3f * s);
            w1[j] = (f16)(__expf(s - mv) * sv);
        }
#pragma unroll
        for (int j = 0; j < 4; ++j) {
            float s = pv * q3[j];
            s = fmaxf(s, 0.3f * s);
            w1[4 + j] = (f16)(__expf(s - mv) * sv);
        }
        __syncthreads();
        *(f16x8*)&As[wn * LDK + half * 16]     = w0;
        *(f16x8*)&As[wn * LDK + half * 16 + 8] = w1;
        *(f16x8*)&Bs[wn * LDK + half * 16]     = b0;
        *(f16x8*)&Bs[wn * LDK + half * 16 + 8] = b1;
        __syncthreads();
        f16x8 af[4], bfr[4];
#pragma unroll
        for (int i = 0; i < 4; ++i) af[i] = *(const f16x8*)&As[(wr * 64 + i * 16 + c) * LDK + g * 8];
#pragma unroll
        for (int jj = 0; jj < 4; ++jj) bfr[jj] = *(const f16x8*)&Bs[(wc * 64 + jj * 16 + c) * LDK + g * 8];
#pragma unroll
        for (int i = 0; i < 4; ++i)
#pragma unroll
            for (int jj = 0; jj < 4; ++jj)
                acc[i][jj] = __builtin_amdgcn_mfma_f32_16x16x32_f16(af[i], bfr[jj], acc[i][jj], 0, 0, 0);
    }
#pragma unroll
    for (int jj = 0; jj < 4; ++jj) {
        int f = f0 + wc * 64 + jj * 16 + c;
#pragma unroll
        for (int i = 0; i < 4; ++i) {
            int r0 = n0 + wr * 64 + i * 16 + g * 4;
#pragma unroll
            for (int rr = 0; rr < 4; ++rr)
                g_oacc[((size_t)h * NN + r0 + rr) * FF + f] = acc[i][jj][rr];
        }
    }
}

// ---------------- final: out = relu(sum_h oacc) (fp32 out) ----------------
__global__ void k_reduce(float* __restrict__ out) {
    size_t i = ((size_t)blockIdx.x * 256 + threadIdx.x) * 4;   // 2048 blocks
    const size_t NF = (size_t)NN * FF;
    f32x4 s = *(const f32x4*)(g_oacc + i);
    s = s + *(const f32x4*)(g_oacc + NF + i);
    s = s + *(const f32x4*)(g_oacc + 2 * NF + i);
    s = s + *(const f32x4*)(g_oacc + 3 * NF + i);
    f32x4 o;
#pragma unroll
    for (int rr = 0; rr < 4; ++rr) o[rr] = fmaxf(s[rr], 0.f);
    *(f32x4*)(out + i) = o;
}

extern "C" void kernel_launch(void* const* d_in, const int* in_sizes, int n_in,
                              void* d_out, int out_size, void* d_ws, size_t ws_size,
                              hipStream_t stream) {
    (void)in_sizes; (void)n_in; (void)out_size; (void)d_ws; (void)ws_size;
    const float* nodes  = (const float*)d_in[0];
    const float* edges  = (const float*)d_in[1];
    const float* labels = (const float*)d_in[2];
    const float* We     = (const float*)d_in[3];
    const float* be     = (const float*)d_in[4];
    const float* W      = (const float*)d_in[5];
    const float* b      = (const float*)d_in[6];
    const float* u      = (const float*)d_in[7];
    const float* v      = (const float*)d_in[8];

    k_convert<<<21514, 256, 0, stream>>>(nodes, edges, labels, We, W, be, b);
    k_uvproj<<<513, 256, 0, stream>>>(W, b, u, v);
    k_pq<<<4096, 256, 0, stream>>>();
    k_gemm_e<<<dim3(32, 8), 256, 0, stream>>>();
    k_gemm_feats<<<dim3(32, 8, 4), 256, 0, stream>>>();
    k_msz<<<dim3(256, 4), 256, 0, stream>>>();
    k_gemm_out<<<dim3(32, 4, 4), 256, 0, stream>>>();
    k_reduce<<<2048, 256, 0, stream>>>((float*)d_out);
}